// Round 18
// baseline (133.497 us; speedup 1.0000x reference)
//
#include <hip/hip_runtime.h>

#define NW    16
#define NEUR  128
#define NPTS  65536
#define SIGMA 0.02f
#define U_MEAN 0.0f
#define U_SD   1.0f
#define DELTA 0.15f          // cull radius; measured absmax bit-identical 0.19->0.15

#define SCALE2L 2.8853900817779268f   // 2*log2(e): folds tanh 2x and exp->exp2 mul
#define WINK    72.13475204444817f    // log2(e)/SIGMA for window exp2

#define TILE   64           // points per block (4 waves x 16 rows)
#define NTHR   256
#define HPAD   136          // h2 row stride: 272B, 16B-aligned (R2: 132 -> misaligned-b128 replay)
#define MAT_HALVES 16384                  // frag-linear fp16 matrix: 128x128 (R10-verified layout)
#define WT_HALVES (2*NW*MAT_HALVES)       // 1,048,576 B
#define WT_BYTES (WT_HALVES*2)
#define CNT_OFF  WT_BYTES                 // 256 ints
#define IDX_OFF  (WT_BYTES + 1024)        // segmented u16 lists, 1 MB
#define BIAS_OFF (IDX_OFF + NW*16*2048*2) // 6144 floats: s*b_in, s*b_hid
#define NSEG   16
#define SEGPTS (NPTS/NSEG)
#define CAPSEG 2048                       // max fill ~1560 at DELTA=0.15
#define CHUNKS 512

typedef _Float16 half8 __attribute__((ext_vector_type(8)));
typedef float    f32x4 __attribute__((ext_vector_type(4)));

typedef const __attribute__((address_space(1))) void* gptr_t;
typedef       __attribute__((address_space(3))) void* lptr_t;

// 4-instr tanh on pre-scaled arg y = 2*log2(e)*x (R16/R17-verified)
__device__ __forceinline__ float tanh_pre(float y) {
    float e = __builtin_amdgcn_exp2f(y);
    return 1.0f - 2.0f * __builtin_amdgcn_rcpf(1.0f + e);
}

// ONE aux dispatch (unchanged from R17):
//   [0,32) prep wt=SCALE2L*W_hid frag-linear | [32,288) bucket | [288,320) zero out + bias2
__global__ __launch_bounds__(512) void aux_kernel(
    const float* __restrict__ W_hid, const float* __restrict__ x,
    const float* __restrict__ mids,  const float* __restrict__ b_in,
    const float* __restrict__ b_hid, _Float16* __restrict__ wt,
    int* __restrict__ cnt16, unsigned short* __restrict__ idx,
    float* __restrict__ bias2, float* __restrict__ out)
{
    const int b = blockIdx.x;
    const int t = threadIdx.x;

    if (b < 32) {                          // ---- prep: one 128x128 matrix per block
        __shared__ __align__(16) _Float16 tile[NEUR * HPAD];   // transpose staging
        const int lw = b;
        const float4* src = (const float4*)(W_hid + (size_t)lw * NEUR * NEUR);
#pragma unroll
        for (int it = 0; it < 8; ++it) {   // 4096 float4, coalesced over e
            int f4 = it * 512 + t;
            int d  = f4 >> 5;
            int e0 = (f4 & 31) << 2;
            float4 v = src[f4];
            tile[(e0 + 0) * HPAD + d] = (_Float16)(SCALE2L * v.x);
            tile[(e0 + 1) * HPAD + d] = (_Float16)(SCALE2L * v.y);
            tile[(e0 + 2) * HPAD + d] = (_Float16)(SCALE2L * v.z);
            tile[(e0 + 3) * HPAD + d] = (_Float16)(SCALE2L * v.w);
        }
        __syncthreads();
        half8* dst8 = (half8*)(wt + (size_t)lw * MAT_HALVES);  // 2048 half8 chunks
#pragma unroll
        for (int it = 0; it < 4; ++it) {
            int h8 = it * 512 + t;
            int sc = h8 >> 6;              // s*8+c
            int ln = h8 & 63;              // lane = q*16+m
            int s_ = sc >> 3, c_ = sc & 7;
            int q_ = ln >> 4, m_ = ln & 15;
            dst8[h8] = *(const half8*)&tile[(c_ * 16 + m_) * HPAD + s_ * 32 + q_ * 8];
        }
    } else if (b < 288) {                  // ---- bucket: (segment, window)
        const int s = (b - 32) & (NSEG - 1);
        const int w = (b - 32) >> 4;
        __shared__ int lcnt;
        if (t == 0) lcnt = 0;
        __syncthreads();
        const float lo = mids[w] - DELTA;
        const float hi = mids[w + 1] + DELTA;
        const int lane = t & 63;
        unsigned short* dst = idx + (size_t)(w * NSEG + s) * CAPSEG;
#pragma unroll
        for (int it = 0; it < SEGPTS / 512; ++it) {
            int i = s * SEGPTS + it * 512 + t;
            float xv = x[i];
            bool need = (xv >= lo) && (xv <= hi);
            unsigned long long mask = __ballot(need);
            if (mask) {
                int leader = (int)__builtin_ctzll(mask);
                int total  = (int)__popcll(mask);
                int rank   = (int)__popcll(mask & ((1ull << lane) - 1ull));
                int base = 0;
                if (lane == leader) base = atomicAdd(&lcnt, total);   // LDS atomic
                base = __shfl(base, leader);
                int slot = base + rank;
                if (need && slot < CAPSEG) dst[slot] = (unsigned short)i;
            }
        }
        __syncthreads();
        if (t == 0) cnt16[w * NSEG + s] = lcnt;
    } else {                               // ---- zero out[]; bias prescale in block 288
        int i4 = (b - 288) * 512 + t;
        float4 z = {0.f, 0.f, 0.f, 0.f};
        ((float4*)out)[i4] = z;
        if (b == 288) {
#pragma unroll
            for (int i = t; i < 6144; i += 512) {
                float v = (i < 2048) ? b_in[i] : b_hid[i - 2048];
                bias2[i] = SCALE2L * v;
            }
        }
    }
}

__global__ __launch_bounds__(NTHR, 3) void fbpinn_main(
    const float* __restrict__ x,     const float* __restrict__ means,
    const float* __restrict__ stds,  const float* __restrict__ mids,
    const float* __restrict__ W_in,  const float* __restrict__ bias2,
    const float* __restrict__ W_out, const float* __restrict__ b_out,
    const _Float16* __restrict__ wt, const int* __restrict__ cnt16,
    const unsigned short* __restrict__ idx, float* __restrict__ out)
{
    const int w    = blockIdx.y;
    const int base = blockIdx.x * TILE;

    // uniform scan of cnt16 (scalar loads); uniform exit
    int csh[NSEG];
    int total = 0;
#pragma unroll
    for (int k = 0; k < NSEG; ++k) {
        int c = cnt16[w * NSEG + k];
        c = c > CAPSEG ? CAPSEG : c;
        csh[k] = c;
        total += c;
    }
    if (base >= total) return;
    const int nvalid = min(TILE, total - base);

    __shared__ __align__(16) _Float16 Wb[MAT_HALVES];    // 32768 B, frag-linear (sW0 then sW1)
    __shared__ __align__(16) _Float16 Hl[TILE * HPAD];   // 17408 B (h2)

    const int t    = threadIdx.x;
    const int lane = t & 63;
    const int wave = t >> 6;           // 0..3
    const int m    = lane & 15;
    const int q    = lane >> 4;
    const int row0 = wave * 16;
    const int rsel = m & 3;

    // stage s*W0 via direct global->LDS
    {
        const char* gb = (const char*)(wt + (size_t)(0 * NW + w) * MAT_HALVES) + t * 16;
        char*       lb = (char*)Wb + wave * 64 * 16;
#pragma unroll
        for (int i = 0; i < 8; ++i)
            __builtin_amdgcn_global_load_lds((gptr_t)(gb + i * 4096), (lptr_t)(lb + i * 4096), 16, 0, 0);
    }

    // per-thread gather of own point (row0+m); true-running-prefix scan (R7 fix)
    int v = base + min(row0 + m, nvalid - 1);
    int seg = 0, segbase = 0, pre = 0;
#pragma unroll
    for (int k = 0; k < NSEG - 1; ++k) {
        pre += csh[k];
        if (v >= pre) { seg = k + 1; segbase = pre; }
    }
    const int   gi = idx[(size_t)(w * NSEG + seg) * CAPSEG + (v - segbase)];
    const float xv = x[gi];

    // L0 into GEMM1 A-fragments; xn carries the 2*log2e prescale
    const float xn = SCALE2L * (xv - means[w]) * __builtin_amdgcn_rcpf(stds[w]);
    const float* win  = W_in + w * NEUR;
    const float* bin2 = bias2 + w * NEUR;
    half8 af[4];
#pragma unroll
    for (int s = 0; s < 4; ++s) {
        const int n0 = s * 32 + q * 8;
        float4 wv0 = *(const float4*)&win[n0];
        float4 wv1 = *(const float4*)&win[n0 + 4];
        float4 bv0 = *(const float4*)&bin2[n0];
        float4 bv1 = *(const float4*)&bin2[n0 + 4];
        af[s][0] = (_Float16)tanh_pre(fmaf(xn, wv0.x, bv0.x));
        af[s][1] = (_Float16)tanh_pre(fmaf(xn, wv0.y, bv0.y));
        af[s][2] = (_Float16)tanh_pre(fmaf(xn, wv0.z, bv0.z));
        af[s][3] = (_Float16)tanh_pre(fmaf(xn, wv0.w, bv0.w));
        af[s][4] = (_Float16)tanh_pre(fmaf(xn, wv1.x, bv1.x));
        af[s][5] = (_Float16)tanh_pre(fmaf(xn, wv1.y, bv1.y));
        af[s][6] = (_Float16)tanh_pre(fmaf(xn, wv1.z, bv1.z));
        af[s][7] = (_Float16)tanh_pre(fmaf(xn, wv1.w, bv1.w));
    }
    __syncthreads();   // barrier 1: W0 landed + visible

    // GEMM1 FUSED with h2-tanh per tile c (R18): tile c's tanh overlaps tile
    // c+1's MFMAs — within-wave VALU/MFMA/LDS overlap instead of phase-serial.
    // h2 kept in fp16 registers; Hl stores deferred below the W1 prefetch.
    const half8* B = (const half8*)Wb;
    const f32x4 zz = {0.f, 0.f, 0.f, 0.f};
    const float* bh0 = bias2 + 2048 + w * NEUR;        // s*b_hid[0]
    _Float16 hreg[32];                                  // 16 VGPRs packed
#pragma unroll
    for (int c = 0; c < 8; ++c) {
        f32x4 a = zz;
#pragma unroll
        for (int s = 0; s < 4; ++s)
            a = __builtin_amdgcn_mfma_f32_16x16x32_f16(af[s], B[(s * 8 + c) * 64 + lane], a, 0, 0, 0);
        float bb = bh0[c * 16 + m];
        hreg[c * 4 + 0] = (_Float16)tanh_pre(a[0] + bb);
        hreg[c * 4 + 1] = (_Float16)tanh_pre(a[1] + bb);
        hreg[c * 4 + 2] = (_Float16)tanh_pre(a[2] + bb);
        hreg[c * 4 + 3] = (_Float16)tanh_pre(a[3] + bb);
    }
    __syncthreads();   // barrier 2: all waves done reading W0

    // issue s*W1 global->LDS; h2 stores below partially cover its latency
    {
        const char* gb = (const char*)(wt + (size_t)(1 * NW + w) * MAT_HALVES) + t * 16;
        char*       lb = (char*)Wb + wave * 64 * 16;
#pragma unroll
        for (int i = 0; i < 8; ++i)
            __builtin_amdgcn_global_load_lds((gptr_t)(gb + i * 4096), (lptr_t)(lb + i * 4096), 16, 0, 0);
    }
#pragma unroll
    for (int c = 0; c < 8; ++c) {
#pragma unroll
        for (int r = 0; r < 4; ++r)
            Hl[(row0 + q * 4 + r) * HPAD + c * 16 + m] = hreg[c * 4 + r];
    }
    __syncthreads();   // barrier 3: W1 landed + h2 visible

    // GEMM2 FUSED with epilogue per tile c. A-frags hoisted (c-invariant).
    half8 ag[4];
#pragma unroll
    for (int s = 0; s < 4; ++s)
        ag[s] = *(const half8*)(Hl + (row0 + m) * HPAD + s * 32 + q * 8);

    const float* bh1 = bias2 + 2048 + (NW + w) * NEUR; // s*b_hid[1]
    const float* wo  = W_out + w * NEUR;
    float t0 = 0.f, t1 = 0.f, t2 = 0.f, t3 = 0.f;
#pragma unroll
    for (int c = 0; c < 8; ++c) {
        f32x4 a = zz;
#pragma unroll
        for (int s = 0; s < 4; ++s)
            a = __builtin_amdgcn_mfma_f32_16x16x32_f16(ag[s], B[(s * 8 + c) * 64 + lane], a, 0, 0, 0);
        float b  = bh1[c * 16 + m];
        float wc = wo[c * 16 + m];
        t0 = fmaf(tanh_pre(a[0] + b), wc, t0);
        t1 = fmaf(tanh_pre(a[1] + b), wc, t1);
        t2 = fmaf(tanh_pre(a[2] + b), wc, t2);
        t3 = fmaf(tanh_pre(a[3] + b), wc, t3);
    }
    t0 += __shfl_xor(t0, 1); t1 += __shfl_xor(t1, 1);
    t2 += __shfl_xor(t2, 1); t3 += __shfl_xor(t3, 1);
    t0 += __shfl_xor(t0, 2); t1 += __shfl_xor(t1, 2);
    t2 += __shfl_xor(t2, 2); t3 += __shfl_xor(t3, 2);
    float vsum = (rsel == 0) ? t0 : (rsel == 1) ? t1 : (rsel == 2) ? t2 : t3;
    vsum += __shfl_xor(vsum, 4);
    vsum += __shfl_xor(vsum, 8);

    // point data for slot = row0 + q*4 + rsel lives at lane 20*q + rsel (R12-verified)
    const int   slot  = row0 + q * 4 + rsel;
    const float xslot = __shfl(xv, 20 * q + rsel);
    const int   gslot = __shfl(gi, 20 * q + rsel);
    if (m < 4 && slot < nvalid) {
        float u   = (vsum + b_out[w]) * U_SD + U_MEAN;
        float xl2 = (xslot - mids[w])     * WINK;
        float xr2 = (xslot - mids[w + 1]) * WINK;
        float wf  = __builtin_amdgcn_rcpf(1.0f + __builtin_amdgcn_exp2f(xl2)) *
                    __builtin_amdgcn_rcpf(1.0f + __builtin_amdgcn_exp2f(-xr2));
        atomicAdd(&out[gslot], wf * u);
    }
}

extern "C" void kernel_launch(void* const* d_in, const int* in_sizes, int n_in,
                              void* d_out, int out_size, void* d_ws, size_t ws_size,
                              hipStream_t stream) {
    const float* x     = (const float*)d_in[0];
    const float* means = (const float*)d_in[1];
    const float* stds  = (const float*)d_in[2];
    const float* mids  = (const float*)d_in[3];
    const float* W_in  = (const float*)d_in[4];
    const float* b_in  = (const float*)d_in[5];
    const float* W_hid = (const float*)d_in[6];
    const float* b_hid = (const float*)d_in[7];
    const float* W_out = (const float*)d_in[8];
    const float* b_out = (const float*)d_in[9];
    float* out = (float*)d_out;

    _Float16*       wt    = (_Float16*)d_ws;                           // 1,048,576 B
    int*            cnt16 = (int*)((char*)d_ws + CNT_OFF);             // 1 KB
    unsigned short* idx   = (unsigned short*)((char*)d_ws + IDX_OFF);  // 1 MB
    float*          bias2 = (float*)((char*)d_ws + BIAS_OFF);          // 24 KB (total ~2.12 MB)

    aux_kernel<<<320, 512, 0, stream>>>(W_hid, x, mids, b_in, b_hid, wt, cnt16, idx, bias2, out);
    fbpinn_main<<<dim3(CHUNKS, NW), NTHR, 0, stream>>>(
        x, means, stds, mids, W_in, bias2, W_out, b_out, wt, cnt16, idx, out);
}

// Round 19
// 133.451 us; speedup vs baseline: 1.0003x; 1.0003x over previous
//
#include <hip/hip_runtime.h>

#define NW    16
#define NEUR  128
#define NPTS  65536
#define SIGMA 0.02f
#define U_MEAN 0.0f
#define U_SD   1.0f
#define DELTA 0.15f          // cull radius; measured absmax bit-identical 0.19->0.15

#define SCALE2L 2.8853900817779268f   // 2*log2(e): folds tanh 2x and exp->exp2 mul
#define WINK    72.13475204444817f    // log2(e)/SIGMA for window exp2

#define TILE   64           // points per block (4 waves x 16 rows)
#define NTHR   256
#define HPAD   136          // h2 row stride: 272B, 16B-aligned (R2: 132 -> misaligned-b128 replay)
#define MAT_HALVES 16384                  // frag-linear fp16 matrix: 128x128 (R10-verified layout)
#define WT_HALVES (2*NW*MAT_HALVES)       // 1,048,576 B
#define WT_BYTES (WT_HALVES*2)
#define CNT_OFF  WT_BYTES                 // 256 ints
#define IDX_OFF  (WT_BYTES + 1024)        // segmented u16 lists, 1 MB
#define BIAS_OFF (IDX_OFF + NW*16*2048*2) // 6144 floats: s*b_in, s*b_hid
#define NSEG   16
#define SEGPTS (NPTS/NSEG)
#define CAPSEG 2048                       // max fill ~1560 at DELTA=0.15
#define CHUNKS 512

typedef _Float16 half8 __attribute__((ext_vector_type(8)));
typedef float    f32x4 __attribute__((ext_vector_type(4)));

typedef const __attribute__((address_space(1))) void* gptr_t;
typedef       __attribute__((address_space(3))) void* lptr_t;

// 4-instr tanh on pre-scaled arg y = 2*log2(e)*x (R16/R17-verified).
// R18 lesson: keep tanh in separate phases from MFMA — fusing per-c broke the
// 8-chain MFMA ILP (dependent 4-MFMA chains, VALUBusy 57->52, main 65.6->71us).
__device__ __forceinline__ float tanh_pre(float y) {
    float e = __builtin_amdgcn_exp2f(y);
    return 1.0f - 2.0f * __builtin_amdgcn_rcpf(1.0f + e);
}

// ONE aux dispatch:
//   [0,32) prep wt=SCALE2L*W_hid frag-linear | [32,288) bucket | [288,320) zero out + bias2
__global__ __launch_bounds__(512) void aux_kernel(
    const float* __restrict__ W_hid, const float* __restrict__ x,
    const float* __restrict__ mids,  const float* __restrict__ b_in,
    const float* __restrict__ b_hid, _Float16* __restrict__ wt,
    int* __restrict__ cnt16, unsigned short* __restrict__ idx,
    float* __restrict__ bias2, float* __restrict__ out)
{
    const int b = blockIdx.x;
    const int t = threadIdx.x;

    if (b < 32) {                          // ---- prep: one 128x128 matrix per block
        __shared__ __align__(16) _Float16 tile[NEUR * HPAD];   // transpose staging
        const int lw = b;
        const float4* src = (const float4*)(W_hid + (size_t)lw * NEUR * NEUR);
#pragma unroll
        for (int it = 0; it < 8; ++it) {   // 4096 float4, coalesced over e
            int f4 = it * 512 + t;
            int d  = f4 >> 5;
            int e0 = (f4 & 31) << 2;
            float4 v = src[f4];
            tile[(e0 + 0) * HPAD + d] = (_Float16)(SCALE2L * v.x);
            tile[(e0 + 1) * HPAD + d] = (_Float16)(SCALE2L * v.y);
            tile[(e0 + 2) * HPAD + d] = (_Float16)(SCALE2L * v.z);
            tile[(e0 + 3) * HPAD + d] = (_Float16)(SCALE2L * v.w);
        }
        __syncthreads();
        half8* dst8 = (half8*)(wt + (size_t)lw * MAT_HALVES);  // 2048 half8 chunks
#pragma unroll
        for (int it = 0; it < 4; ++it) {
            int h8 = it * 512 + t;
            int sc = h8 >> 6;              // s*8+c
            int ln = h8 & 63;              // lane = q*16+m
            int s_ = sc >> 3, c_ = sc & 7;
            int q_ = ln >> 4, m_ = ln & 15;
            dst8[h8] = *(const half8*)&tile[(c_ * 16 + m_) * HPAD + s_ * 32 + q_ * 8];
        }
    } else if (b < 288) {                  // ---- bucket: (segment, window)
        const int s = (b - 32) & (NSEG - 1);
        const int w = (b - 32) >> 4;
        __shared__ int lcnt;
        if (t == 0) lcnt = 0;
        __syncthreads();
        const float lo = mids[w] - DELTA;
        const float hi = mids[w + 1] + DELTA;
        const int lane = t & 63;
        unsigned short* dst = idx + (size_t)(w * NSEG + s) * CAPSEG;
#pragma unroll
        for (int it = 0; it < SEGPTS / 512; ++it) {
            int i = s * SEGPTS + it * 512 + t;
            float xv = x[i];
            bool need = (xv >= lo) && (xv <= hi);
            unsigned long long mask = __ballot(need);
            if (mask) {
                int leader = (int)__builtin_ctzll(mask);
                int total  = (int)__popcll(mask);
                int rank   = (int)__popcll(mask & ((1ull << lane) - 1ull));
                int base = 0;
                if (lane == leader) base = atomicAdd(&lcnt, total);   // LDS atomic
                base = __shfl(base, leader);
                int slot = base + rank;
                if (need && slot < CAPSEG) dst[slot] = (unsigned short)i;
            }
        }
        __syncthreads();
        if (t == 0) cnt16[w * NSEG + s] = lcnt;
    } else {                               // ---- zero out[]; bias prescale in block 288
        int i4 = (b - 288) * 512 + t;
        float4 z = {0.f, 0.f, 0.f, 0.f};
        ((float4*)out)[i4] = z;
        if (b == 288) {
#pragma unroll
            for (int i = t; i < 6144; i += 512) {
                float v = (i < 2048) ? b_in[i] : b_hid[i - 2048];
                bias2[i] = SCALE2L * v;
            }
        }
    }
}

__global__ __launch_bounds__(NTHR, 3) void fbpinn_main(
    const float* __restrict__ x,     const float* __restrict__ means,
    const float* __restrict__ stds,  const float* __restrict__ mids,
    const float* __restrict__ W_in,  const float* __restrict__ bias2,
    const float* __restrict__ W_out, const float* __restrict__ b_out,
    const _Float16* __restrict__ wt, const int* __restrict__ cnt16,
    const unsigned short* __restrict__ idx, float* __restrict__ out)
{
    const int w    = blockIdx.y;
    const int base = blockIdx.x * TILE;

    // uniform scan of cnt16 (scalar loads); uniform exit
    int csh[NSEG];
    int total = 0;
#pragma unroll
    for (int k = 0; k < NSEG; ++k) {
        int c = cnt16[w * NSEG + k];
        c = c > CAPSEG ? CAPSEG : c;
        csh[k] = c;
        total += c;
    }
    if (base >= total) return;
    const int nvalid = min(TILE, total - base);

    __shared__ __align__(16) _Float16 Wb[MAT_HALVES];    // 32768 B, frag-linear (sW0 then sW1)
    __shared__ __align__(16) _Float16 Hl[TILE * HPAD];   // 17408 B (h2)

    const int t    = threadIdx.x;
    const int lane = t & 63;
    const int wave = t >> 6;           // 0..3
    const int m    = lane & 15;
    const int q    = lane >> 4;
    const int row0 = wave * 16;
    const int rsel = m & 3;

    // stage s*W0 via direct global->LDS (R12: register prefetch spills; this doesn't)
    {
        const char* gb = (const char*)(wt + (size_t)(0 * NW + w) * MAT_HALVES) + t * 16;
        char*       lb = (char*)Wb + wave * 64 * 16;
#pragma unroll
        for (int i = 0; i < 8; ++i)
            __builtin_amdgcn_global_load_lds((gptr_t)(gb + i * 4096), (lptr_t)(lb + i * 4096), 16, 0, 0);
    }

    // per-thread gather of own point (row0+m); true-running-prefix scan (R7 fix)
    int v = base + min(row0 + m, nvalid - 1);
    int seg = 0, segbase = 0, pre = 0;
#pragma unroll
    for (int k = 0; k < NSEG - 1; ++k) {
        pre += csh[k];
        if (v >= pre) { seg = k + 1; segbase = pre; }
    }
    const int   gi = idx[(size_t)(w * NSEG + seg) * CAPSEG + (v - segbase)];
    const float xv = x[gi];

    // L0 into GEMM1 A-fragments; xn carries the full 2*log2e prescale
    const float xn = SCALE2L * (xv - means[w]) * __builtin_amdgcn_rcpf(stds[w]);
    const float* win  = W_in + w * NEUR;
    const float* bin2 = bias2 + w * NEUR;              // s*b_in
    half8 af[4];
#pragma unroll
    for (int s = 0; s < 4; ++s) {
        const int n0 = s * 32 + q * 8;
        float4 wv0 = *(const float4*)&win[n0];
        float4 wv1 = *(const float4*)&win[n0 + 4];
        float4 bv0 = *(const float4*)&bin2[n0];
        float4 bv1 = *(const float4*)&bin2[n0 + 4];
        af[s][0] = (_Float16)tanh_pre(fmaf(xn, wv0.x, bv0.x));
        af[s][1] = (_Float16)tanh_pre(fmaf(xn, wv0.y, bv0.y));
        af[s][2] = (_Float16)tanh_pre(fmaf(xn, wv0.z, bv0.z));
        af[s][3] = (_Float16)tanh_pre(fmaf(xn, wv0.w, bv0.w));
        af[s][4] = (_Float16)tanh_pre(fmaf(xn, wv1.x, bv1.x));
        af[s][5] = (_Float16)tanh_pre(fmaf(xn, wv1.y, bv1.y));
        af[s][6] = (_Float16)tanh_pre(fmaf(xn, wv1.z, bv1.z));
        af[s][7] = (_Float16)tanh_pre(fmaf(xn, wv1.w, bv1.w));
    }
    __syncthreads();   // barrier 1: W0 landed (vmcnt drained) + visible

    // GEMM1: acc = h1 @ (sW0)^T = s*z2; s-outer/c-inner -> 8 independent MFMA chains
    const half8* B = (const half8*)Wb;
    f32x4 acc[8];
    const f32x4 zz = {0.f, 0.f, 0.f, 0.f};
#pragma unroll
    for (int c = 0; c < 8; ++c) acc[c] = zz;
#pragma unroll
    for (int s = 0; s < 4; ++s)
#pragma unroll
        for (int c = 0; c < 8; ++c)
            acc[c] = __builtin_amdgcn_mfma_f32_16x16x32_f16(af[s], B[(s * 8 + c) * 64 + lane], acc[c], 0, 0, 0);

    __syncthreads();   // barrier 2: all waves done reading W0

    // issue s*W1 global->LDS now; latency hides under the h2-tanh block below
    {
        const char* gb = (const char*)(wt + (size_t)(1 * NW + w) * MAT_HALVES) + t * 16;
        char*       lb = (char*)Wb + wave * 64 * 16;
#pragma unroll
        for (int i = 0; i < 8; ++i)
            __builtin_amdgcn_global_load_lds((gptr_t)(gb + i * 4096), (lptr_t)(lb + i * 4096), 16, 0, 0);
    }

    // h2 = tanh_pre(s*z2 + s*b) -> Hl own rows (same-wave dep for GEMM2 A-reads)
    {
        const float* bh0 = bias2 + 2048 + w * NEUR;    // s*b_hid[0]
#pragma unroll
        for (int c = 0; c < 8; ++c) {
            float bb = bh0[c * 16 + m];
#pragma unroll
            for (int r = 0; r < 4; ++r)
                Hl[(row0 + q * 4 + r) * HPAD + c * 16 + m] = (_Float16)tanh_pre(acc[c][r] + bb);
        }
    }
    __syncthreads();   // barrier 3: W1 landed (vmcnt drained) + visible

    // GEMM2: acc = h2 @ (sW1)^T = s*z3
#pragma unroll
    for (int c = 0; c < 8; ++c) acc[c] = zz;
#pragma unroll
    for (int s = 0; s < 4; ++s) {
        half8 a = *(const half8*)(Hl + (row0 + m) * HPAD + s * 32 + q * 8);
#pragma unroll
        for (int c = 0; c < 8; ++c)
            acc[c] = __builtin_amdgcn_mfma_f32_16x16x32_f16(a, B[(s * 8 + c) * 64 + lane], acc[c], 0, 0, 0);
    }

    // epilogue: h3 = tanh_pre(s*z3 + s*b); dot W_out; reduce over 16 m-lanes
    const float* bh1 = bias2 + 2048 + (NW + w) * NEUR; // s*b_hid[1]
    const float* wo  = W_out + w * NEUR;
    float t0 = 0.f, t1 = 0.f, t2 = 0.f, t3 = 0.f;
#pragma unroll
    for (int c = 0; c < 8; ++c) {
        float b  = bh1[c * 16 + m];
        float wc = wo[c * 16 + m];
        t0 = fmaf(tanh_pre(acc[c][0] + b), wc, t0);
        t1 = fmaf(tanh_pre(acc[c][1] + b), wc, t1);
        t2 = fmaf(tanh_pre(acc[c][2] + b), wc, t2);
        t3 = fmaf(tanh_pre(acc[c][3] + b), wc, t3);
    }
    t0 += __shfl_xor(t0, 1); t1 += __shfl_xor(t1, 1);
    t2 += __shfl_xor(t2, 1); t3 += __shfl_xor(t3, 1);
    t0 += __shfl_xor(t0, 2); t1 += __shfl_xor(t1, 2);
    t2 += __shfl_xor(t2, 2); t3 += __shfl_xor(t3, 2);
    float vsum = (rsel == 0) ? t0 : (rsel == 1) ? t1 : (rsel == 2) ? t2 : t3;
    vsum += __shfl_xor(vsum, 4);
    vsum += __shfl_xor(vsum, 8);

    // point data for slot = row0 + q*4 + rsel lives at lane 20*q + rsel (R12-verified)
    const int   slot  = row0 + q * 4 + rsel;
    const float xslot = __shfl(xv, 20 * q + rsel);
    const int   gslot = __shfl(gi, 20 * q + rsel);
    if (m < 4 && slot < nvalid) {
        float u   = (vsum + b_out[w]) * U_SD + U_MEAN;
        float xl2 = (xslot - mids[w])     * WINK;
        float xr2 = (xslot - mids[w + 1]) * WINK;
        float wf  = __builtin_amdgcn_rcpf(1.0f + __builtin_amdgcn_exp2f(xl2)) *
                    __builtin_amdgcn_rcpf(1.0f + __builtin_amdgcn_exp2f(-xr2));
        atomicAdd(&out[gslot], wf * u);
    }
}

extern "C" void kernel_launch(void* const* d_in, const int* in_sizes, int n_in,
                              void* d_out, int out_size, void* d_ws, size_t ws_size,
                              hipStream_t stream) {
    const float* x     = (const float*)d_in[0];
    const float* means = (const float*)d_in[1];
    const float* stds  = (const float*)d_in[2];
    const float* mids  = (const float*)d_in[3];
    const float* W_in  = (const float*)d_in[4];
    const float* b_in  = (const float*)d_in[5];
    const float* W_hid = (const float*)d_in[6];
    const float* b_hid = (const float*)d_in[7];
    const float* W_out = (const float*)d_in[8];
    const float* b_out = (const float*)d_in[9];
    float* out = (float*)d_out;

    _Float16*       wt    = (_Float16*)d_ws;                           // 1,048,576 B
    int*            cnt16 = (int*)((char*)d_ws + CNT_OFF);             // 1 KB
    unsigned short* idx   = (unsigned short*)((char*)d_ws + IDX_OFF);  // 1 MB
    float*          bias2 = (float*)((char*)d_ws + BIAS_OFF);          // 24 KB (total ~2.12 MB)

    aux_kernel<<<320, 512, 0, stream>>>(W_hid, x, mids, b_in, b_hid, wt, cnt16, idx, bias2, out);
    fbpinn_main<<<dim3(CHUNKS, NW), NTHR, 0, stream>>>(
        x, means, stds, mids, W_in, bias2, W_out, b_out, wt, cnt16, idx, out);
}